// Round 6
// baseline (300.426 us; speedup 1.0000x reference)
//
#include <hip/hip_runtime.h>
#include <cstdint>
#include <cstddef>

typedef unsigned short u16;
typedef __attribute__((ext_vector_type(8))) short short8;
typedef __attribute__((ext_vector_type(4))) float v4f;

static constexpr size_t NN = (size_t)2048 * 2048;
#define N2 2048

typedef __attribute__((address_space(1))) const unsigned int guint;
typedef __attribute__((address_space(3))) unsigned int luint;

__device__ __forceinline__ float b2f_bits(uint32_t hi) { union { uint32_t u; float f; } v; v.u = hi; return v.f; }
__device__ __forceinline__ float b2f(u16 x) { return b2f_bits((uint32_t)x << 16); }
__device__ __forceinline__ u16 f2b(float f) {
  union { float f; uint32_t u; } v; v.f = f;
  uint32_t r = v.u + 0x7fffu + ((v.u >> 16) & 1u);
  return (u16)(r >> 16);
}
__device__ __forceinline__ uint4 pack8(const float* f) {
  uint4 u;
  u.x = (uint32_t)f2b(f[0]) | ((uint32_t)f2b(f[1]) << 16);
  u.y = (uint32_t)f2b(f[2]) | ((uint32_t)f2b(f[3]) << 16);
  u.z = (uint32_t)f2b(f[4]) | ((uint32_t)f2b(f[5]) << 16);
  u.w = (uint32_t)f2b(f[6]) | ((uint32_t)f2b(f[7]) << 16);
  return u;
}
// wave-uniform value -> SGPR
__device__ __forceinline__ float sgprf(float x) {
  union { float f; int i; } v; v.f = x;
  v.i = __builtin_amdgcn_readfirstlane(v.i);
  return v.f;
}

// ---------------------------------------------------------------------------
// K0: one pass over fp32 A[5][N][N], 64x64 tiles, 512 threads. Outputs abf,
// a1r row-major; bbt, a1t transposed via XOR-swizzled LDS (two-phase, 16 KB).
// Every block zeroes its 512-float slice of Z|T; block 0 zeroes counters.
// Xw^T fold: blocks by<16 (512 of 1024), 4 rows each, 2 threads per (n,k)
// element (128-iteration halves + shfl combine) -- R5's all-blocks spread put
// the serial GEMV on every block's critical path (occupancy 35->23%, +18us).
// ---------------------------------------------------------------------------
__global__ __launch_bounds__(512, 2) void conv_kernel(
    const float* __restrict__ A, const float* __restrict__ w1,
    const float* __restrict__ w2, const float* __restrict__ w3,
    const float* __restrict__ X, const float* __restrict__ W,
    u16* __restrict__ abf, u16* __restrict__ bbt, u16* __restrict__ a1t,
    u16* __restrict__ a1r, u16* __restrict__ Xwt,
    float* __restrict__ zeroZT, int* __restrict__ counters)
{
  __shared__ u16 LT[2][64 * 64];   // [b_c, a1_c], transposed+swizzled
  const int t = threadIdx.x;
  const int bid = (int)(blockIdx.y * 32 + blockIdx.x);
  const int i0 = blockIdx.y * 64, j0 = blockIdx.x * 64;
  const int m = t >> 3;            // tile row 0..63
  const int cg = t & 7;            // colgroup 0..7
  const int n0 = cg * 8;           // col base

  zeroZT[(size_t)bid * 512 + t] = 0.f;            // Z|T zero (524288 floats)
  if (bid == 0 && t < 64) counters[t] = 0;

  // softmax weights -> SGPRs
  float sc[3][2][5];
  {
    const float* wsrc[3] = { w1, w2, w3 };
    for (int q = 0; q < 3; ++q)
      for (int c = 0; c < 2; ++c) {
        float v[5], mx = -1e30f, sum = 0.f;
        #pragma unroll
        for (int e = 0; e < 5; ++e) { v[e] = wsrc[q][c * 5 + e]; mx = fmaxf(mx, v[e]); }
        #pragma unroll
        for (int e = 0; e < 5; ++e) { v[e] = expf(v[e] - mx); sum += v[e]; }
        #pragma unroll
        for (int e = 0; e < 5; ++e) sc[q][c][e] = sgprf(v[e] / sum);
      }
  }

  float av[2][8], bv[2][8], cv[2][8];
  #pragma unroll
  for (int c = 0; c < 2; ++c)
    #pragma unroll
    for (int u = 0; u < 8; ++u) { av[c][u] = 0.f; bv[c][u] = 0.f; cv[c][u] = 0.f; }

  #pragma unroll
  for (int e = 0; e < 5; ++e) {
    const float* base = A + (size_t)e * NN + (size_t)(i0 + m) * N2 + (j0 + n0);
    float4 x0 = ((const float4*)base)[0];
    float4 x1 = ((const float4*)base)[1];
    float f[8] = { x0.x, x0.y, x0.z, x0.w, x1.x, x1.y, x1.z, x1.w };
    #pragma unroll
    for (int c = 0; c < 2; ++c)
      #pragma unroll
      for (int u = 0; u < 8; ++u) {
        av[c][u] += sc[0][c][e] * f[u];
        bv[c][u] += sc[1][c][e] * f[u];
        cv[c][u] += sc[2][c][e] * f[u];
      }
  }

  // row-major outputs: 16B/lane, 8 lanes cover a 128B line
  #pragma unroll
  for (int c = 0; c < 2; ++c) {
    *(uint4*)(abf + (size_t)c * NN + (size_t)(i0 + m) * N2 + (j0 + n0)) = pack8(av[c]);
    *(uint4*)(a1r + (size_t)c * NN + (size_t)(i0 + m) * N2 + (j0 + n0)) = pack8(cv[c]);
  }
  // two-phase transposed stash (swizzled scalar stores, 2-way banks = free)
  const int swb = ((m >> 3) ^ cg) & 7;
  const int mlo = m & 7;
  const int on = t >> 3;          // output row (tile col n)
  const int mb = t & 7;           // m-block
  const int src = on * 64 + (((mb ^ (on >> 3)) & 7) * 8);
  #pragma unroll
  for (int c = 0; c < 2; ++c) {
    if (c == 1) __syncthreads();
    #pragma unroll
    for (int u = 0; u < 8; ++u) {
      const int idx = (n0 + u) * 64 + swb * 8 + mlo;
      LT[0][idx] = f2b(bv[c][u]);
      LT[1][idx] = f2b(cv[c][u]);
    }
    __syncthreads();
    *(uint4*)(bbt + (size_t)c * NN + (size_t)(j0 + on) * N2 + (i0 + mb * 8)) =
        *(const uint4*)&LT[0][src];
    *(uint4*)(a1t + (size_t)c * NN + (size_t)(j0 + on) * N2 + (i0 + mb * 8)) =
        *(const uint4*)&LT[1][src];
  }
  // Folded Xw^T: blocks by<16, 4 rows each; 2 threads per (n,k).
  if (blockIdx.y < 16) {
    const int pair = t >> 1, half = t & 1;
    const int n = (int)(blockIdx.y * 32 + blockIdx.x) * 4 + (pair >> 6);
    const int k = pair & 63;
    float acc = 0.f;
    const int mmb = half * 128;
    for (int mm = mmb; mm < mmb + 128; ++mm)
      acc += X[n * 256 + mm] * W[mm * 64 + k];
    acc += __shfl_xor(acc, 1);
    if (half == 0) Xwt[(size_t)k * N2 + n] = f2b(acc);
  }
}

// ---------------------------------------------------------------------------
// bf16 MFMA GEMM (glds staging, 128x128 tile, BK=64, 256 thr). C = A@B with
// A [M][K] bf16 row-major, Bt [N][K] bf16 K-contiguous. Emits column-sum
// partials csp[c][16][2048], diag[c][2048] (fp32), and Cout = bf16 C^T via
// two-half in-LDS transpose.
// ---------------------------------------------------------------------------
__global__ __launch_bounds__(256, 3) void gemm_kernel(
    const u16* __restrict__ Ain, const u16* __restrict__ Btin,
    u16* __restrict__ Cout, float* __restrict__ csp, float* __restrict__ diag)
{
  const int c = blockIdx.z;
  const u16* Ac = Ain + (size_t)c * NN;
  const u16* Bc = Btin + (size_t)c * NN;
  const int m0 = blockIdx.y * 128, n0 = blockIdx.x * 128;
  const int t = threadIdx.x, w = t >> 6, lane = t & 63;
  const int quad = lane >> 4, r = lane & 15;
  __shared__ u16 SM[128 * 64 + 128 * 64];   // As | Bs (32 KB)
  u16* As = SM;
  u16* Bs = SM + 128 * 64;

  v4f zero4 = { 0.f, 0.f, 0.f, 0.f };
  v4f acc[2][8];
  #pragma unroll
  for (int i = 0; i < 2; ++i)
    #pragma unroll
    for (int j = 0; j < 8; ++j) acc[i][j] = zero4;

  const int srow = lane >> 3;            // row within an 8-row chunk
  const int sgran = (lane & 7) ^ srow;   // swizzled k-granule

  for (int kt = 0; kt < 2048; kt += 64) {
    __syncthreads();
    #pragma unroll
    for (int i = 0; i < 4; ++i) {
      const int chunk = i * 4 + w;
      const u16* ga = Ac + (size_t)(m0 + chunk * 8 + srow) * N2 + kt + sgran * 8;
      __builtin_amdgcn_global_load_lds((guint*)ga, (luint*)(As + chunk * 512), 16, 0, 0);
    }
    #pragma unroll
    for (int i = 0; i < 4; ++i) {
      const int chunk = i * 4 + w;
      const u16* gb = Bc + (size_t)(n0 + chunk * 8 + srow) * N2 + kt + sgran * 8;
      __builtin_amdgcn_global_load_lds((guint*)gb, (luint*)(Bs + chunk * 512), 16, 0, 0);
    }
    __syncthreads();
    #pragma unroll
    for (int ks = 0; ks < 2; ++ks) {
      const int sl = ((ks * 4 + quad) ^ (r & 7)) * 8;
      short8 af[2], bf[8];
      #pragma unroll
      for (int i = 0; i < 2; ++i)
        af[i] = *(const short8*)(As + (w * 32 + i * 16 + r) * 64 + sl);
      #pragma unroll
      for (int j = 0; j < 8; ++j)
        bf[j] = *(const short8*)(Bs + (j * 16 + r) * 64 + sl);
      #pragma unroll
      for (int i = 0; i < 2; ++i)
        #pragma unroll
        for (int j = 0; j < 8; ++j)
          acc[i][j] = __builtin_amdgcn_mfma_f32_16x16x32_bf16(af[i], bf[j], acc[i][j], 0, 0, 0);
    }
  }
  // C/D layout: col=lane&15, row=quad*4+reg (m89-verified). Diagonal fp32.
  if (blockIdx.x == blockIdx.y) {
    #pragma unroll
    for (int i = 0; i < 2; ++i) {
      const int rowg = m0 + w * 32 + i * 16 + quad * 4;
      #pragma unroll
      for (int j = 0; j < 8; ++j) {
        const int colg = n0 + j * 16 + r;
        #pragma unroll
        for (int g = 0; g < 4; ++g)
          if (rowg + g == colg) diag[c * N2 + colg] = acc[i][j][g];
      }
    }
  }
  // Column-sum partials over this block's 128 rows for its 128 cols.
  float s[8];
  #pragma unroll
  for (int j = 0; j < 8; ++j) {
    s[j] = 0.f;
    #pragma unroll
    for (int i = 0; i < 2; ++i)
      #pragma unroll
      for (int g = 0; g < 4; ++g) s[j] += acc[i][j][g];
    s[j] += __shfl_xor(s[j], 16);
    s[j] += __shfl_xor(s[j], 32);
  }
  __syncthreads();                 // MFMA-loop LDS reads done
  float* csl = (float*)SM;         // [4][128]
  if (quad == 0) {
    #pragma unroll
    for (int j = 0; j < 8; ++j) csl[w * 128 + j * 16 + r] = s[j];
  }
  __syncthreads();
  if (t < 128) {
    const float v = csl[t] + csl[128 + t] + csl[256 + t] + csl[384 + t];
    csp[((size_t)(c * 16) + blockIdx.y) * N2 + n0 + t] = v;
  }
  // Two-half transpose via LDS (row stride 136 u16 = 272 B, 16-B aligned).
  {
    u16* tb = SM;                  // [64][136] u16 = 17.4 KB
    u16* Cc = Cout + (size_t)c * NN;
    #pragma unroll
    for (int h = 0; h < 2; ++h) {
      __syncthreads();
      #pragma unroll
      for (int i = 0; i < 2; ++i) {
        #pragma unroll
        for (int jl = 0; jl < 4; ++jl) {
          const int j = h * 4 + jl;
          #pragma unroll
          for (int g = 0; g < 4; ++g)
            tb[(jl * 16 + r) * 136 + (w * 32 + i * 16 + quad * 4 + g)] = f2b(acc[i][j][g]);
        }
      }
      __syncthreads();
      const int rown = t >> 2, seg = t & 3;
      const u16* ps = tb + rown * 136 + seg * 32;
      uint4* pd = (uint4*)(Cc + (size_t)(n0 + h * 64 + rown) * N2 + m0 + seg * 32);
      pd[0] = ((const uint4*)ps)[0];
      pd[1] = ((const uint4*)ps)[1];
      pd[2] = ((const uint4*)ps)[2];
      pd[3] = ((const uint4*)ps)[3];
    }
  }
}

// ---------------------------------------------------------------------------
// zgemm: per block (mt, split, c), K-split 16 (512 blocks, 2/CU):
//   1) MFMA Z-tile partial over j in split's 128-range; atomicAdd into
//      Z[c][k][i] (fp32, 1 MB, L2-resident; zeroed by conv).
//   2) ci/wv slice for its 128 i-rows from csp/diag1 (L2-hot).
//   3) dcol elementwise over its (i x j) region: Ht (L2-hot) + a1r (HBM)
//      -> dp/cp direct stores [c][16 m-tiles][2048] (distinct 128-slices).
// ---------------------------------------------------------------------------
__global__ __launch_bounds__(256, 4) void zgemm_kernel(
    const u16* __restrict__ Ht, const u16* __restrict__ Xwt,
    const u16* __restrict__ a1r, const float* __restrict__ csp,
    const float* __restrict__ diag1, float* __restrict__ Z,
    float* __restrict__ dp, float* __restrict__ cp)
{
  const int c = blockIdx.z, split = blockIdx.y, mt = blockIdx.x;
  const int m0 = mt * 128;
  const u16* Ac = Ht + (size_t)c * NN;
  const int t = threadIdx.x, w = t >> 6, lane = t & 63;
  const int quad = lane >> 4, r = lane & 15;
  __shared__ u16 SMZ[128 * 64 + 64 * 64];   // As | Bs (24 KB)
  u16* As = SMZ;
  u16* Bs = SMZ + 128 * 64;

  v4f zero4 = { 0.f, 0.f, 0.f, 0.f };
  v4f acc[2][4];
  #pragma unroll
  for (int i = 0; i < 2; ++i)
    #pragma unroll
    for (int j = 0; j < 4; ++j) acc[i][j] = zero4;

  const int srow = lane >> 3;
  const int sgran = (lane & 7) ^ srow;

  #pragma unroll
  for (int kk = 0; kk < 2; ++kk) {
    const int kt = split * 128 + kk * 64;
    __syncthreads();
    #pragma unroll
    for (int i = 0; i < 4; ++i) {
      const int chunk = i * 4 + w;
      const u16* ga = Ac + (size_t)(m0 + chunk * 8 + srow) * N2 + kt + sgran * 8;
      __builtin_amdgcn_global_load_lds((guint*)ga, (luint*)(As + chunk * 512), 16, 0, 0);
    }
    #pragma unroll
    for (int i = 0; i < 2; ++i) {
      const int chunk = i * 4 + w;
      const u16* gb = Xwt + (size_t)(chunk * 8 + srow) * N2 + kt + sgran * 8;
      __builtin_amdgcn_global_load_lds((guint*)gb, (luint*)(Bs + chunk * 512), 16, 0, 0);
    }
    __syncthreads();
    #pragma unroll
    for (int ks = 0; ks < 2; ++ks) {
      const int sl = ((ks * 4 + quad) ^ (r & 7)) * 8;
      short8 af[2], bf[4];
      #pragma unroll
      for (int i = 0; i < 2; ++i)
        af[i] = *(const short8*)(As + (w * 32 + i * 16 + r) * 64 + sl);
      #pragma unroll
      for (int j = 0; j < 4; ++j)
        bf[j] = *(const short8*)(Bs + (j * 16 + r) * 64 + sl);
      #pragma unroll
      for (int i = 0; i < 2; ++i)
        #pragma unroll
        for (int j = 0; j < 4; ++j)
          acc[i][j] = __builtin_amdgcn_mfma_f32_16x16x32_bf16(af[i], bf[j], acc[i][j], 0, 0, 0);
    }
  }
  // atomic accumulate into Z[c][k][i]
  #pragma unroll
  for (int i = 0; i < 2; ++i) {
    const int rowg = m0 + w * 32 + i * 16 + quad * 4;
    #pragma unroll
    for (int j = 0; j < 4; ++j) {
      const int colg = j * 16 + r;
      float* base = Z + (size_t)(c * 64 + colg) * N2 + rowg;
      #pragma unroll
      for (int g = 0; g < 4; ++g)
        atomicAdd(base + g, acc[i][j][g]);
    }
  }
  // --- ci/wv slice for this block's 128 rows (into LDS floats [0..256)) ---
  __syncthreads();                       // MFMA LDS reads done; reuse SMZ
  float* ci_l = (float*)SMZ;             // [128]
  float* wv_l = ci_l + 128;              // [128]
  if (t < 128) {
    const int i = m0 + t;
    float cs = 0.f;
    #pragma unroll
    for (int s = 0; s < 16; ++s) cs += csp[((size_t)(c * 16) + s) * N2 + i];
    const float deg = cs - diag1[c * N2 + i];
    const float v = (deg == 0.f) ? 0.f : 1.f / (deg + 1e-8f);
    ci_l[t] = v;
    wv_l[t] = v * deg;
  }
  __syncthreads();
  // --- dcol elementwise: thread = 4 cols (j4) x 8-row group (ig) per kk ---
  const int j4 = (t & 15) * 4, ig = t >> 4;
  float dacc[2][4], cacc[2][4];
  #pragma unroll
  for (int kk = 0; kk < 2; ++kk) {
    const int gj = split * 128 + kk * 64 + j4;
    #pragma unroll
    for (int u = 0; u < 4; ++u) { dacc[kk][u] = 0.f; cacc[kk][u] = 0.f; }
    for (int ii = 0; ii < 8; ++ii) {
      const int i = m0 + ig * 8 + ii;
      uint2 hu = *(const uint2*)(Ht  + (size_t)c * NN + (size_t)i * N2 + gj);
      uint2 au = *(const uint2*)(a1r + (size_t)c * NN + (size_t)i * N2 + gj);
      float h[4], a[4];
      h[0] = b2f_bits(hu.x << 16); h[1] = b2f_bits(hu.x & 0xffff0000u);
      h[2] = b2f_bits(hu.y << 16); h[3] = b2f_bits(hu.y & 0xffff0000u);
      a[0] = b2f_bits(au.x << 16); a[1] = b2f_bits(au.x & 0xffff0000u);
      a[2] = b2f_bits(au.y << 16); a[3] = b2f_bits(au.y & 0xffff0000u);
      const float cq = ci_l[ig * 8 + ii];
      const float wq = wv_l[ig * 8 + ii];
      #pragma unroll
      for (int u = 0; u < 4; ++u) {
        cacc[kk][u] += wq * a[u];
        const float tv = cq * h[u] * a[u];
        dacc[kk][u] += (i == gj + u) ? 0.f : tv;
      }
    }
  }
  // reduce over 16 ig-groups via LDS; dacc in cols [0,128), cacc in [128,256)
  float* red = ci_l + 256;               // [16][256] floats = 16 KB
  __syncthreads();
  #pragma unroll
  for (int kk = 0; kk < 2; ++kk)
    #pragma unroll
    for (int u = 0; u < 4; ++u) {
      red[ig * 256 + kk * 64 + j4 + u] = dacc[kk][u];
      red[ig * 256 + 128 + kk * 64 + j4 + u] = cacc[kk][u];
    }
  __syncthreads();
  {
    float v = 0.f;
    #pragma unroll
    for (int g = 0; g < 16; ++g) v += red[g * 256 + t];
    if (t < 128)
      dp[((size_t)(c * 16) + mt) * N2 + split * 128 + t] = v;
    else
      cp[((size_t)(c * 16) + mt) * N2 + split * 128 + (t - 128)] = v;
  }
}

// ---------------------------------------------------------------------------
// tgemm: per block (mt, split, c), K-split 16 (512 blocks, 2/CU):
//   prologue: ci/diag1 slice for its 128 j's; compute B-panel
//     Bp[k][j'] = bf16(ci*(Z[c][k][j'] - d1*xw)) into swizzled LDS (yfix
//     fused; Z/csp/Xwt are L2-resident; 2 threads per column).
//   MFMA over j-range (A = a1t staged via glds); atomicAdd into T[c][i][k].
//   micro-tail: last-of-16-splits per (mt,c) reads T (32 KB L2) + dp/cp, does
//   fin + relu epilogue for its 128 rows -> out.
// ---------------------------------------------------------------------------
__global__ __launch_bounds__(256, 4) void tgemm_kernel(
    const u16* __restrict__ a1t, const float* __restrict__ csp,
    const float* __restrict__ diag1, const float* __restrict__ Z,
    const u16* __restrict__ Xwt, const float* __restrict__ dp,
    const float* __restrict__ cp, float* __restrict__ T,
    float* __restrict__ out, int* __restrict__ counters)
{
  const int c = blockIdx.z, split = blockIdx.y, mt = blockIdx.x;
  const int m0 = mt * 128, kt0 = split * 128;
  const int t = threadIdx.x, w = t >> 6, lane = t & 63;
  const int quad = lane >> 4, r = lane & 15;
  __shared__ u16 As[128 * 64];       // 16 KB, staged per kk
  __shared__ u16 Bp[64 * 128];       // 16 KB, computed once (swizzled)
  __shared__ float cif[128], d1f[128];

  const int jl = t & 127;
  // ci/d1 slice for jj in [kt0, kt0+128)
  if (t < 128) {
    const int jj = kt0 + jl;
    float cs = 0.f;
    #pragma unroll
    for (int s = 0; s < 16; ++s) cs += csp[((size_t)(c * 16) + s) * N2 + jj];
    const float d1 = diag1[c * N2 + jj];
    const float deg = cs - d1;
    cif[jl] = (deg == 0.f) ? 0.f : 1.f / (deg + 1e-8f);
    d1f[jl] = d1;
  }
  __syncthreads();
  // B panel: 2 threads own column jl (k-halves); swizzle granule g^(k&7)
  // within each 64-wide chunk (matches MFMA read's sl). 2-way banks (free).
  {
    const int kkc = jl >> 6, g = (jl >> 3) & 7, el = jl & 7;
    const int kh = (t >> 7) * 32;
    const float civ = cif[jl], d1v = d1f[jl];
    const float* zcol = Z + (size_t)(c * 64) * N2 + kt0 + jl;
    const u16* xcol = Xwt + kt0 + jl;
    for (int k = kh; k < kh + 32; ++k) {
      const float z = zcol[(size_t)k * N2];
      const float xw = b2f(xcol[(size_t)k * N2]);
      Bp[k * 128 + kkc * 64 + ((g ^ (k & 7)) * 8) + el] = f2b(civ * (z - d1v * xw));
    }
  }

  v4f zero4 = { 0.f, 0.f, 0.f, 0.f };
  v4f acc[2][4];
  #pragma unroll
  for (int i = 0; i < 2; ++i)
    #pragma unroll
    for (int j = 0; j < 4; ++j) acc[i][j] = zero4;

  const int srow = lane >> 3;
  const int sgran = (lane & 7) ^ srow;

  #pragma unroll
  for (int kk = 0; kk < 2; ++kk) {
    const int kt = kt0 + kk * 64;
    __syncthreads();               // (kk=0: also covers Bp writes)
    #pragma unroll
    for (int i = 0; i < 4; ++i) {
      const int chunk = i * 4 + w;
      const u16* ga = a1t + (size_t)c * NN + (size_t)(m0 + chunk * 8 + srow) * N2 + kt + sgran * 8;
      __builtin_amdgcn_global_load_lds((guint*)ga, (luint*)(As + chunk * 512), 16, 0, 0);
    }
    __syncthreads();
    #pragma unroll
    for (int ks = 0; ks < 2; ++ks) {
      const int sl = ((ks * 4 + quad) ^ (r & 7)) * 8;
      short8 af[2], bf[4];
      #pragma unroll
      for (int i = 0; i < 2; ++i)
        af[i] = *(const short8*)(As + (w * 32 + i * 16 + r) * 64 + sl);
      #pragma unroll
      for (int j = 0; j < 4; ++j)
        bf[j] = *(const short8*)(Bp + (j * 16 + r) * 128 + kk * 64 + sl);
      #pragma unroll
      for (int i = 0; i < 2; ++i)
        #pragma unroll
        for (int j = 0; j < 4; ++j)
          acc[i][j] = __builtin_amdgcn_mfma_f32_16x16x32_bf16(af[i], bf[j], acc[i][j], 0, 0, 0);
    }
  }
  // atomic accumulate into T[c][i][k]
  #pragma unroll
  for (int i = 0; i < 2; ++i) {
    const int rowg = m0 + w * 32 + i * 16 + quad * 4;
    #pragma unroll
    for (int j = 0; j < 4; ++j) {
      const int colg = j * 16 + r;
      float* base = T + ((size_t)(c * 2048) + rowg) * 64 + colg;
      #pragma unroll
      for (int g = 0; g < 4; ++g)
        atomicAdd(base + (size_t)g * 64, acc[i][j][g]);
    }
  }
  // --- micro-tail: fin + epilogue for this m-tile (last of 16 splits) ---
  __shared__ int eLast;
  __syncthreads();                 // drains this block's atomics (vmcnt 0)
  if (t == 0) {
    __threadfence();
    eLast = (atomicAdd(&counters[mt * 2 + c], 1) == 15);
  }
  __syncthreads();
  if (eLast) {
    __threadfence();               // acquire: see other blocks' T atomics
    const int i = m0 + (t >> 1), kh = (t & 1) * 32;
    float ds = 0.f, cs = 0.f;
    #pragma unroll
    for (int b = 0; b < 16; ++b) {
      ds += dp[((size_t)(c * 16) + b) * N2 + i];
      cs += cp[((size_t)(c * 16) + b) * N2 + i];
    }
    const float deg = cs - ds + 1.0f;   // add=True diag contributes +1
    const float dv = (deg == 0.f) ? 0.f : 1.f / (deg + 1e-8f);
    #pragma unroll
    for (int k2 = 0; k2 < 32; ++k2) {
      const int k = kh + k2;
      const float Tv = T[((size_t)(c * 2048) + i) * 64 + k];
      const float xw = b2f(Xwt[(size_t)k * N2 + i]);
      float v = dv * (Tv - ds * xw + xw);
      v = v > 0.f ? v : 0.f;
      out[(size_t)i * 128 + c * 64 + k] = v;
    }
  }
}

// ---------------------------------------------------------------------------
// Workspace layout (bytes), ~87.05 MB, all reads preceded by writes:
//   abf   @ 0          (16.78 MB bf16)  -- dead after gemm1
//   bbt   @ 16777216   (16.78 MB bf16)  -- dead after gemm1
//   a1t   @ 33554432   (16.78 MB bf16)  -- dead after tgemm
//   a1r   @ 50331648   (16.78 MB bf16)  -- dead after zgemm
//   Ht    @ 67108864   (16.78 MB bf16)  -- dead after zgemm
//   Xwt   @ 83886080   (256 KB bf16 [64][2048])
//   cspa  @ 84148224   (256 KB fp32 [2][16][2048])
//   diag1 @ 84410368   (16 KB)
//   dp    @ 84426752   (256 KB fp32 [2][16][2048])
//   cp    @ 84688896   (256 KB)
//   Z     @ 84951040   (1 MB fp32 [2][64][2048], zeroed by conv)
//   T     @ 85999616   (1 MB fp32 [2][2048][64], zeroed by conv)
//   cnt   @ 87048192   (256 B)          -- end 87048448
// ---------------------------------------------------------------------------
extern "C" void kernel_launch(void* const* d_in, const int* in_sizes, int n_in,
                              void* d_out, int out_size, void* d_ws, size_t ws_size,
                              hipStream_t stream) {
  const float* A  = (const float*)d_in[0];
  const float* X  = (const float*)d_in[1];
  const float* w1 = (const float*)d_in[2];
  const float* w2 = (const float*)d_in[3];
  const float* w3 = (const float*)d_in[4];
  const float* W  = (const float*)d_in[5];
  float* out = (float*)d_out;
  char* ws = (char*)d_ws;

  u16*   abf   = (u16*)(ws + 0);
  u16*   bbt   = (u16*)(ws + 16777216);
  u16*   a1t   = (u16*)(ws + 33554432);
  u16*   a1r   = (u16*)(ws + 50331648);
  u16*   Ht    = (u16*)(ws + 67108864);
  u16*   Xwt   = (u16*)(ws + 83886080);
  float* cspa  = (float*)(ws + 84148224);
  float* diag1 = (float*)(ws + 84410368);
  float* dp    = (float*)(ws + 84426752);
  float* cp    = (float*)(ws + 84688896);
  float* Z     = (float*)(ws + 84951040);
  float* T     = (float*)(ws + 85999616);
  int*   cnt   = (int*)  (ws + 87048192);

  conv_kernel<<<dim3(32, 32), 512, 0, stream>>>(A, w1, w2, w3, X, W, abf, bbt, a1t, a1r, Xwt, Z, cnt);
  gemm_kernel<<<dim3(16, 16, 2), 256, 0, stream>>>(abf, bbt, Ht, cspa, diag1);
  zgemm_kernel<<<dim3(16, 16, 2), 256, 0, stream>>>(Ht, Xwt, a1r, cspa, diag1, Z, dp, cp);
  tgemm_kernel<<<dim3(16, 16, 2), 256, 0, stream>>>(a1t, cspa, diag1, Z, Xwt, dp, cp, T, out, cnt);
}

// Round 7
// 245.831 us; speedup vs baseline: 1.2221x; 1.2221x over previous
//
#include <hip/hip_runtime.h>
#include <cstdint>
#include <cstddef>

typedef unsigned short u16;
typedef __attribute__((ext_vector_type(8))) short short8;
typedef __attribute__((ext_vector_type(4))) float v4f;

static constexpr size_t NN = (size_t)2048 * 2048;
#define N2 2048

typedef __attribute__((address_space(1))) const unsigned int guint;
typedef __attribute__((address_space(3))) unsigned int luint;

__device__ __forceinline__ float b2f_bits(uint32_t hi) { union { uint32_t u; float f; } v; v.u = hi; return v.f; }
__device__ __forceinline__ float b2f(u16 x) { return b2f_bits((uint32_t)x << 16); }
__device__ __forceinline__ u16 f2b(float f) {
  union { float f; uint32_t u; } v; v.f = f;
  uint32_t r = v.u + 0x7fffu + ((v.u >> 16) & 1u);
  return (u16)(r >> 16);
}
__device__ __forceinline__ uint4 pack8(const float* f) {
  uint4 u;
  u.x = (uint32_t)f2b(f[0]) | ((uint32_t)f2b(f[1]) << 16);
  u.y = (uint32_t)f2b(f[2]) | ((uint32_t)f2b(f[3]) << 16);
  u.z = (uint32_t)f2b(f[4]) | ((uint32_t)f2b(f[5]) << 16);
  u.w = (uint32_t)f2b(f[6]) | ((uint32_t)f2b(f[7]) << 16);
  return u;
}
__device__ __forceinline__ void unp8(uint4 u, float* f) {
  f[0] = b2f_bits(u.x << 16); f[1] = b2f_bits(u.x & 0xffff0000u);
  f[2] = b2f_bits(u.y << 16); f[3] = b2f_bits(u.y & 0xffff0000u);
  f[4] = b2f_bits(u.z << 16); f[5] = b2f_bits(u.z & 0xffff0000u);
  f[6] = b2f_bits(u.w << 16); f[7] = b2f_bits(u.w & 0xffff0000u);
}
// wave-uniform value -> SGPR
__device__ __forceinline__ float sgprf(float x) {
  union { float f; int i; } v; v.f = x;
  v.i = __builtin_amdgcn_readfirstlane(v.i);
  return v.f;
}

// ---------------------------------------------------------------------------
// K0 (R4's measured-best 50.2us variant, counters/zeroing removed): one pass
// over fp32 A[5][N][N], 64x64 tiles, 512 threads. abf, a1r row-major; bbt,
// a1t transposed via XOR-swizzled two-phase LDS (16 KB). Blocks by<8 fold in
// Xw^T (8 rows each, 1 thread per element, 256-iter serial GEMV).
// ---------------------------------------------------------------------------
__global__ __launch_bounds__(512, 2) void conv_kernel(
    const float* __restrict__ A, const float* __restrict__ w1,
    const float* __restrict__ w2, const float* __restrict__ w3,
    const float* __restrict__ X, const float* __restrict__ W,
    u16* __restrict__ abf, u16* __restrict__ bbt, u16* __restrict__ a1t,
    u16* __restrict__ a1r, u16* __restrict__ Xwt)
{
  __shared__ u16 LT[2][64 * 64];   // [b_c, a1_c], transposed+swizzled
  const int t = threadIdx.x;
  const int i0 = blockIdx.y * 64, j0 = blockIdx.x * 64;
  const int m = t >> 3;            // tile row 0..63
  const int cg = t & 7;            // colgroup 0..7
  const int n0 = cg * 8;           // col base

  // softmax weights -> SGPRs
  float sc[3][2][5];
  {
    const float* wsrc[3] = { w1, w2, w3 };
    for (int q = 0; q < 3; ++q)
      for (int c = 0; c < 2; ++c) {
        float v[5], mx = -1e30f, sum = 0.f;
        #pragma unroll
        for (int e = 0; e < 5; ++e) { v[e] = wsrc[q][c * 5 + e]; mx = fmaxf(mx, v[e]); }
        #pragma unroll
        for (int e = 0; e < 5; ++e) { v[e] = expf(v[e] - mx); sum += v[e]; }
        #pragma unroll
        for (int e = 0; e < 5; ++e) sc[q][c][e] = sgprf(v[e] / sum);
      }
  }

  float av[2][8], bv[2][8], cv[2][8];
  #pragma unroll
  for (int c = 0; c < 2; ++c)
    #pragma unroll
    for (int u = 0; u < 8; ++u) { av[c][u] = 0.f; bv[c][u] = 0.f; cv[c][u] = 0.f; }

  #pragma unroll
  for (int e = 0; e < 5; ++e) {
    const float* base = A + (size_t)e * NN + (size_t)(i0 + m) * N2 + (j0 + n0);
    float4 x0 = ((const float4*)base)[0];
    float4 x1 = ((const float4*)base)[1];
    float f[8] = { x0.x, x0.y, x0.z, x0.w, x1.x, x1.y, x1.z, x1.w };
    #pragma unroll
    for (int c = 0; c < 2; ++c)
      #pragma unroll
      for (int u = 0; u < 8; ++u) {
        av[c][u] += sc[0][c][e] * f[u];
        bv[c][u] += sc[1][c][e] * f[u];
        cv[c][u] += sc[2][c][e] * f[u];
      }
  }

  // row-major outputs: 16B/lane, 8 lanes cover a 128B line
  #pragma unroll
  for (int c = 0; c < 2; ++c) {
    *(uint4*)(abf + (size_t)c * NN + (size_t)(i0 + m) * N2 + (j0 + n0)) = pack8(av[c]);
    *(uint4*)(a1r + (size_t)c * NN + (size_t)(i0 + m) * N2 + (j0 + n0)) = pack8(cv[c]);
  }
  // two-phase transposed stash (swizzled scalar stores, 2-way banks = free)
  const int swb = ((m >> 3) ^ cg) & 7;
  const int mlo = m & 7;
  const int on = t >> 3;          // output row (tile col n)
  const int mb = t & 7;           // m-block
  const int src = on * 64 + (((mb ^ (on >> 3)) & 7) * 8);
  #pragma unroll
  for (int c = 0; c < 2; ++c) {
    if (c == 1) __syncthreads();
    #pragma unroll
    for (int u = 0; u < 8; ++u) {
      const int idx = (n0 + u) * 64 + swb * 8 + mlo;
      LT[0][idx] = f2b(bv[c][u]);
      LT[1][idx] = f2b(cv[c][u]);
    }
    __syncthreads();
    *(uint4*)(bbt + (size_t)c * NN + (size_t)(j0 + on) * N2 + (i0 + mb * 8)) =
        *(const uint4*)&LT[0][src];
    *(uint4*)(a1t + (size_t)c * NN + (size_t)(j0 + on) * N2 + (i0 + mb * 8)) =
        *(const uint4*)&LT[1][src];
  }
  // Folded Xw^T: 256 blocks x 8 rows = 2048 rows.
  if (blockIdx.y < 8) {
    const int n = (int)(blockIdx.y * 32 + blockIdx.x) * 8 + (t >> 6);
    const int k = t & 63;
    float acc = 0.f;
    for (int mm = 0; mm < 256; ++mm)
      acc += X[n * 256 + mm] * W[mm * 64 + k];
    Xwt[(size_t)k * N2 + n] = f2b(acc);
  }
}

// ---------------------------------------------------------------------------
// bf16 MFMA GEMM (glds staging, 128x128 tile, BK=64, 256 thr). C = A@B with
// A [M][K] bf16 row-major, Bt [N][K] bf16 K-contiguous. Emits column-sum
// partials csp[c][16][2048], diag[c][2048] (fp32), and Cout = bf16 C^T via
// two-half in-LDS transpose.
// ---------------------------------------------------------------------------
__global__ __launch_bounds__(256, 3) void gemm_kernel(
    const u16* __restrict__ Ain, const u16* __restrict__ Btin,
    u16* __restrict__ Cout, float* __restrict__ csp, float* __restrict__ diag)
{
  const int c = blockIdx.z;
  const u16* Ac = Ain + (size_t)c * NN;
  const u16* Bc = Btin + (size_t)c * NN;
  const int m0 = blockIdx.y * 128, n0 = blockIdx.x * 128;
  const int t = threadIdx.x, w = t >> 6, lane = t & 63;
  const int quad = lane >> 4, r = lane & 15;
  __shared__ u16 SM[128 * 64 + 128 * 64];   // As | Bs (32 KB)
  u16* As = SM;
  u16* Bs = SM + 128 * 64;

  v4f zero4 = { 0.f, 0.f, 0.f, 0.f };
  v4f acc[2][8];
  #pragma unroll
  for (int i = 0; i < 2; ++i)
    #pragma unroll
    for (int j = 0; j < 8; ++j) acc[i][j] = zero4;

  const int srow = lane >> 3;            // row within an 8-row chunk
  const int sgran = (lane & 7) ^ srow;   // swizzled k-granule

  for (int kt = 0; kt < 2048; kt += 64) {
    __syncthreads();
    #pragma unroll
    for (int i = 0; i < 4; ++i) {
      const int chunk = i * 4 + w;
      const u16* ga = Ac + (size_t)(m0 + chunk * 8 + srow) * N2 + kt + sgran * 8;
      __builtin_amdgcn_global_load_lds((guint*)ga, (luint*)(As + chunk * 512), 16, 0, 0);
    }
    #pragma unroll
    for (int i = 0; i < 4; ++i) {
      const int chunk = i * 4 + w;
      const u16* gb = Bc + (size_t)(n0 + chunk * 8 + srow) * N2 + kt + sgran * 8;
      __builtin_amdgcn_global_load_lds((guint*)gb, (luint*)(Bs + chunk * 512), 16, 0, 0);
    }
    __syncthreads();
    #pragma unroll
    for (int ks = 0; ks < 2; ++ks) {
      const int sl = ((ks * 4 + quad) ^ (r & 7)) * 8;
      short8 af[2], bf[8];
      #pragma unroll
      for (int i = 0; i < 2; ++i)
        af[i] = *(const short8*)(As + (w * 32 + i * 16 + r) * 64 + sl);
      #pragma unroll
      for (int j = 0; j < 8; ++j)
        bf[j] = *(const short8*)(Bs + (j * 16 + r) * 64 + sl);
      #pragma unroll
      for (int i = 0; i < 2; ++i)
        #pragma unroll
        for (int j = 0; j < 8; ++j)
          acc[i][j] = __builtin_amdgcn_mfma_f32_16x16x32_bf16(af[i], bf[j], acc[i][j], 0, 0, 0);
    }
  }
  // C/D layout: col=lane&15, row=quad*4+reg (m89-verified). Diagonal fp32.
  if (blockIdx.x == blockIdx.y) {
    #pragma unroll
    for (int i = 0; i < 2; ++i) {
      const int rowg = m0 + w * 32 + i * 16 + quad * 4;
      #pragma unroll
      for (int j = 0; j < 8; ++j) {
        const int colg = n0 + j * 16 + r;
        #pragma unroll
        for (int g = 0; g < 4; ++g)
          if (rowg + g == colg) diag[c * N2 + colg] = acc[i][j][g];
      }
    }
  }
  // Column-sum partials over this block's 128 rows for its 128 cols.
  float s[8];
  #pragma unroll
  for (int j = 0; j < 8; ++j) {
    s[j] = 0.f;
    #pragma unroll
    for (int i = 0; i < 2; ++i)
      #pragma unroll
      for (int g = 0; g < 4; ++g) s[j] += acc[i][j][g];
    s[j] += __shfl_xor(s[j], 16);
    s[j] += __shfl_xor(s[j], 32);
  }
  __syncthreads();                 // MFMA-loop LDS reads done
  float* csl = (float*)SM;         // [4][128]
  if (quad == 0) {
    #pragma unroll
    for (int j = 0; j < 8; ++j) csl[w * 128 + j * 16 + r] = s[j];
  }
  __syncthreads();
  if (t < 128) {
    const float v = csl[t] + csl[128 + t] + csl[256 + t] + csl[384 + t];
    csp[((size_t)(c * 16) + blockIdx.y) * N2 + n0 + t] = v;
  }
  // Two-half transpose via LDS (row stride 136 u16 = 272 B, 16-B aligned).
  {
    u16* tb = SM;                  // [64][136] u16 = 17.4 KB
    u16* Cc = Cout + (size_t)c * NN;
    #pragma unroll
    for (int h = 0; h < 2; ++h) {
      __syncthreads();
      #pragma unroll
      for (int i = 0; i < 2; ++i) {
        #pragma unroll
        for (int jl = 0; jl < 4; ++jl) {
          const int j = h * 4 + jl;
          #pragma unroll
          for (int g = 0; g < 4; ++g)
            tb[(jl * 16 + r) * 136 + (w * 32 + i * 16 + quad * 4 + g)] = f2b(acc[i][j][g]);
        }
      }
      __syncthreads();
      const int rown = t >> 2, seg = t & 3;
      const u16* ps = tb + rown * 136 + seg * 32;
      uint4* pd = (uint4*)(Cc + (size_t)(n0 + h * 64 + rown) * N2 + m0 + seg * 32);
      pd[0] = ((const uint4*)ps)[0];
      pd[1] = ((const uint4*)ps)[1];
      pd[2] = ((const uint4*)ps)[2];
      pd[3] = ((const uint4*)ps)[3];
    }
  }
}

// ---------------------------------------------------------------------------
// zgemm: Zp[split][c][k][i] partial of sum_j Ht[i][j]*Xwt[k][j] over j in
// split's 128-range. K-split 16 -> grid (16,16,2) = 1024 blocks, 2+/CU
// (R3 ran 256 blocks = 1/CU = 12.5% occupancy). Disjoint partial buffers:
// no atomics, no contention, no tails. Blocks (0,0,c) also run colinv.
// ---------------------------------------------------------------------------
__global__ __launch_bounds__(256, 2) void zgemm_kernel(
    const u16* __restrict__ Ht, const u16* __restrict__ Xwt, float* __restrict__ Zp,
    const float* __restrict__ csp, const float* __restrict__ diag,
    float* __restrict__ ci, float* __restrict__ wv)
{
  const int c = blockIdx.z, split = blockIdx.y;
  const int m0 = blockIdx.x * 128;
  const u16* Ac = Ht + (size_t)c * NN;
  const int t = threadIdx.x, w = t >> 6, lane = t & 63;
  const int quad = lane >> 4, r = lane & 15;
  __shared__ u16 As[128 * 64];
  __shared__ u16 Bs[64 * 64];

  v4f zero4 = { 0.f, 0.f, 0.f, 0.f };
  v4f acc[2][4];
  #pragma unroll
  for (int i = 0; i < 2; ++i)
    #pragma unroll
    for (int j = 0; j < 4; ++j) acc[i][j] = zero4;

  const int srow = lane >> 3;
  const int sgran = (lane & 7) ^ srow;

  #pragma unroll
  for (int kk = 0; kk < 2; ++kk) {
    const int kt = split * 128 + kk * 64;
    __syncthreads();
    #pragma unroll
    for (int i = 0; i < 4; ++i) {
      const int chunk = i * 4 + w;
      const u16* ga = Ac + (size_t)(m0 + chunk * 8 + srow) * N2 + kt + sgran * 8;
      __builtin_amdgcn_global_load_lds((guint*)ga, (luint*)(As + chunk * 512), 16, 0, 0);
    }
    #pragma unroll
    for (int i = 0; i < 2; ++i) {
      const int chunk = i * 4 + w;
      const u16* gb = Xwt + (size_t)(chunk * 8 + srow) * N2 + kt + sgran * 8;
      __builtin_amdgcn_global_load_lds((guint*)gb, (luint*)(Bs + chunk * 512), 16, 0, 0);
    }
    __syncthreads();
    #pragma unroll
    for (int ks = 0; ks < 2; ++ks) {
      const int sl = ((ks * 4 + quad) ^ (r & 7)) * 8;
      short8 af[2], bf[4];
      #pragma unroll
      for (int i = 0; i < 2; ++i)
        af[i] = *(const short8*)(As + (w * 32 + i * 16 + r) * 64 + sl);
      #pragma unroll
      for (int j = 0; j < 4; ++j)
        bf[j] = *(const short8*)(Bs + (j * 16 + r) * 64 + sl);
      #pragma unroll
      for (int i = 0; i < 2; ++i)
        #pragma unroll
        for (int j = 0; j < 4; ++j)
          acc[i][j] = __builtin_amdgcn_mfma_f32_16x16x32_bf16(af[i], bf[j], acc[i][j], 0, 0, 0);
    }
  }
  const size_t pbase = (size_t)(split * 2 + c) * 64;
  #pragma unroll
  for (int i = 0; i < 2; ++i) {
    const int rowg = m0 + w * 32 + i * 16 + quad * 4;
    #pragma unroll
    for (int j = 0; j < 4; ++j) {
      const int colg = j * 16 + r;
      *(v4f*)(Zp + (pbase + colg) * (size_t)N2 + rowg) = acc[i][j];
    }
  }
  // Fused colinv for channel c (2 blocks; inputs from previous kernel).
  if (blockIdx.x == 0 && blockIdx.y == 0) {
    for (int q = t; q < 2048; q += 256) {
      float cs = 0.f;
      #pragma unroll
      for (int s = 0; s < 16; ++s) cs += csp[((size_t)(c * 16) + s) * N2 + q];
      const float deg = cs - diag[c * N2 + q];
      const float v = (deg == 0.f) ? 0.f : 1.f / (deg + 1e-8f);
      ci[c * N2 + q] = v;
      wv[c * N2 + q] = v * deg;
    }
  }
}

// ---------------------------------------------------------------------------
// dcol: streaming pass over Ht and a1r rows q. Per-column partials:
//   dacc[p] += ci[q]*Ht[q][p]*a1[q][p]   (q != p)   -> diag(H2) partials
//   cacc[p] += w2v[q]*a1[q][p]                       -> colsum(H2) partials
// Grid (256 row-groups of 8, 2 channels) = 512 blocks, 2/CU (R3: 1/CU).
// Partials dp/cp [c][256][2048] fp32.
// ---------------------------------------------------------------------------
__global__ __launch_bounds__(256, 2) void dcol_kernel(
    const u16* __restrict__ Ht, const u16* __restrict__ a1r,
    const float* __restrict__ ci, const float* __restrict__ wv,
    float* __restrict__ dp, float* __restrict__ cp)
{
  const int qg = blockIdx.x, c = blockIdx.y;
  const int p0 = threadIdx.x * 8;
  float dacc[8] = {0,0,0,0,0,0,0,0};
  float cacc[8] = {0,0,0,0,0,0,0,0};
  const u16* hb = Ht  + (size_t)c * NN + (size_t)(qg * 8) * N2 + p0;
  const u16* ab = a1r + (size_t)c * NN + (size_t)(qg * 8) * N2 + p0;
  for (int qq = 0; qq < 8; ++qq) {
    const int q = qg * 8 + qq;
    const float cq = ci[c * N2 + q];
    const float wq = wv[c * N2 + q];
    uint4 hu = *(const uint4*)(hb + (size_t)qq * N2);
    uint4 au = *(const uint4*)(ab + (size_t)qq * N2);
    float h[8], a[8];
    unp8(hu, h); unp8(au, a);
    #pragma unroll
    for (int u = 0; u < 8; ++u) {
      cacc[u] += wq * a[u];
      const float tv = cq * h[u] * a[u];
      dacc[u] += (p0 + u == q) ? 0.f : tv;
    }
  }
  float* dd = dp + (size_t)(c * 256 + qg) * N2 + p0;
  float* cd = cp + (size_t)(c * 256 + qg) * N2 + p0;
  v4f d0 = { dacc[0], dacc[1], dacc[2], dacc[3] };
  v4f d1 = { dacc[4], dacc[5], dacc[6], dacc[7] };
  v4f c0 = { cacc[0], cacc[1], cacc[2], cacc[3] };
  v4f c1 = { cacc[4], cacc[5], cacc[6], cacc[7] };
  *(v4f*)dd = d0; *(v4f*)(dd + 4) = d1;
  *(v4f*)cd = c0; *(v4f*)(cd + 4) = c1;
}

// yfix: Y^T[c][k][i] = bf16( ci[i] * (Z[i][k] - diag1[i]*Xw[i][k]) ),
// Z reduced from 16 split partials. Blocks 0..15 additionally run fin
// (reduce dp/cp -> diag2/dinv2; inputs complete: dcol precedes this launch).
// ---------------------------------------------------------------------------
__global__ __launch_bounds__(256) void yfix_kernel(
    const float* __restrict__ Zp, const float* __restrict__ ci,
    const float* __restrict__ diag1, const u16* __restrict__ Xwt,
    u16* __restrict__ Yt, const float* __restrict__ dp,
    const float* __restrict__ cp, float* __restrict__ diag2,
    float* __restrict__ dinv2)
{
  const int idx = blockIdx.x * 256 + threadIdx.x;  // [0, 262144)
  const int i = idx & 2047, k = (idx >> 11) & 63, c = idx >> 17;
  float z = 0.f;
  #pragma unroll
  for (int s = 0; s < 16; ++s)
    z += Zp[(size_t)((s * 2 + c) * 64 + k) * N2 + i];
  const float xw = b2f(Xwt[(size_t)k * N2 + i]);
  const float y = ci[c * N2 + i] * (z - diag1[c * N2 + i] * xw);
  Yt[(size_t)c * 64 * N2 + (size_t)k * N2 + i] = f2b(y);
  // fused fin (16 of 1024 blocks)
  if (blockIdx.x < 16) {
    const int idx2 = blockIdx.x * 256 + threadIdx.x;  // [0, 4096)
    const int c2 = idx2 >> 11, i2 = idx2 & 2047;
    float ds = 0.f, cs = 0.f;
    for (int b = 0; b < 256; ++b) {
      ds += dp[(size_t)(c2 * 256 + b) * N2 + i2];
      cs += cp[(size_t)(c2 * 256 + b) * N2 + i2];
    }
    const float deg = cs - ds + 1.0f;   // add=True: diag set to 1 -> +1
    diag2[idx2] = ds;
    dinv2[idx2] = (deg == 0.f) ? 0.f : 1.f / (deg + 1e-8f);
  }
}

// ---------------------------------------------------------------------------
// tgemm: Tp[split][c][i][k] partial of sum_j a1t[i][j]*Yt[c][k][j] over j in
// split's 128-range. K-split 16 -> 1024 blocks, 2+/CU.
// ---------------------------------------------------------------------------
__global__ __launch_bounds__(256, 2) void tgemm_kernel(
    const u16* __restrict__ a1t, const u16* __restrict__ Yt, float* __restrict__ Tp)
{
  const int c = blockIdx.z, split = blockIdx.y;
  const int m0 = blockIdx.x * 128;
  const u16* Ac = a1t + (size_t)c * NN;
  const u16* Bc = Yt + (size_t)c * (64 * (size_t)N2);
  const int t = threadIdx.x, w = t >> 6, lane = t & 63;
  const int quad = lane >> 4, r = lane & 15;
  __shared__ u16 As[128 * 64];
  __shared__ u16 Bs[64 * 64];

  v4f zero4 = { 0.f, 0.f, 0.f, 0.f };
  v4f acc[2][4];
  #pragma unroll
  for (int i = 0; i < 2; ++i)
    #pragma unroll
    for (int j = 0; j < 4; ++j) acc[i][j] = zero4;

  const int srow = lane >> 3;
  const int sgran = (lane & 7) ^ srow;

  #pragma unroll
  for (int kk = 0; kk < 2; ++kk) {
    const int kt = split * 128 + kk * 64;
    __syncthreads();
    #pragma unroll
    for (int i = 0; i < 4; ++i) {
      const int chunk = i * 4 + w;
      const u16* ga = Ac + (size_t)(m0 + chunk * 8 + srow) * N2 + kt + sgran * 8;
      __builtin_amdgcn_global_load_lds((guint*)ga, (luint*)(As + chunk * 512), 16, 0, 0);
    }
    #pragma unroll
    for (int i = 0; i < 2; ++i) {
      const int chunk = i * 4 + w;
      const u16* gb = Bc + (size_t)(chunk * 8 + srow) * N2 + kt + sgran * 8;
      __builtin_amdgcn_global_load_lds((guint*)gb, (luint*)(Bs + chunk * 512), 16, 0, 0);
    }
    __syncthreads();
    #pragma unroll
    for (int ks = 0; ks < 2; ++ks) {
      const int sl = ((ks * 4 + quad) ^ (r & 7)) * 8;
      short8 af[2], bf[4];
      #pragma unroll
      for (int i = 0; i < 2; ++i)
        af[i] = *(const short8*)(As + (w * 32 + i * 16 + r) * 64 + sl);
      #pragma unroll
      for (int j = 0; j < 4; ++j)
        bf[j] = *(const short8*)(Bs + (j * 16 + r) * 64 + sl);
      #pragma unroll
      for (int i = 0; i < 2; ++i)
        #pragma unroll
        for (int j = 0; j < 4; ++j)
          acc[i][j] = __builtin_amdgcn_mfma_f32_16x16x32_bf16(af[i], bf[j], acc[i][j], 0, 0, 0);
    }
  }
  const size_t pbase = (size_t)(split * 2 + c) * 2048;
  #pragma unroll
  for (int i = 0; i < 2; ++i) {
    const int rowg = m0 + w * 32 + i * 16 + quad * 4;
    #pragma unroll
    for (int j = 0; j < 4; ++j) {
      const int colg = j * 16 + r;
      #pragma unroll
      for (int g = 0; g < 4; ++g)
        Tp[(pbase + rowg + g) * 64 + colg] = acc[i][j][g];
    }
  }
}

// out[i][c*64+k] = relu( dinv2 * (T - diag2*xw + xw) ), fp32; T from 16 splits
__global__ void epilogue_kernel(const float* __restrict__ Tp, const float* __restrict__ diag2,
                                const float* __restrict__ dinv2, const u16* __restrict__ Xwt,
                                float* __restrict__ out)
{
  const int idx = blockIdx.x * 256 + threadIdx.x;
  const int k = idx & 63;
  const int c = (idx >> 6) & 1;
  const int i = idx >> 7;
  float T = 0.f;
  #pragma unroll
  for (int s = 0; s < 16; ++s)
    T += Tp[((size_t)(s * 2 + c) * 2048 + i) * 64 + k];
  const float hd = diag2[c * N2 + i];
  const float dv = dinv2[c * N2 + i];
  const float xw = b2f(Xwt[(size_t)k * N2 + i]);
  float v = dv * (T - hd * xw + xw);
  v = v > 0.f ? v : 0.f;
  out[(size_t)i * 128 + c * 64 + k] = v;
}

// ---------------------------------------------------------------------------
// Workspace layout (bytes), all reads preceded by writes, no cross-block sync:
//   abf   @ 0          (16.78 MB bf16)  -- dead after gemm1
//   bbt   @ 16777216   (16.78 MB bf16)  -- dead after gemm1
//   a1t   @ 33554432   (16.78 MB bf16)  -- dead after tgemm
//   a1r   @ 50331648   (16.78 MB bf16)  -- dead after dcol
//   Ht    @ 67108864   (16.78 MB bf16)  -- dead after dcol
//   Xwt   @ 83886080   (256 KB bf16 [64][2048])
//   cspa  @ 84148224   (256 KB fp32 [2][16][2048])
//   diag1 @ 84410368   (16 KB)
//   ci1   @ 84426752   (16 KB)
//   w2v   @ 84443136   (16 KB)
//   diag2 @ 84459520   (16 KB)
//   dinv2 @ 84475904   (16 KB)          -- end 84492288
//   Zp    @ 0          (16.78 MB fp32 [16][2][64][2048], over abf)
//   dp    @ 16777216   (4 MB fp32 [2][256][2048], over bbt)
//   cp    @ 20971520   (4 MB, over bbt)
//   Yt    @ 25165824   (512 KB bf16 [2][64][2048], over bbt)
//   Tp    @ 50331648   (16.78 MB fp32 [16][2][2048][64], over a1r)
// ---------------------------------------------------------------------------
extern "C" void kernel_launch(void* const* d_in, const int* in_sizes, int n_in,
                              void* d_out, int out_size, void* d_ws, size_t ws_size,
                              hipStream_t stream) {
  const float* A  = (const float*)d_in[0];
  const float* X  = (const float*)d_in[1];
  const float* w1 = (const float*)d_in[2];
  const float* w2 = (const float*)d_in[3];
  const float* w3 = (const float*)d_in[4];
  const float* W  = (const float*)d_in[5];
  float* out = (float*)d_out;
  char* ws = (char*)d_ws;

  u16*   abf   = (u16*)(ws + 0);
  u16*   bbt   = (u16*)(ws + 16777216);
  u16*   a1t   = (u16*)(ws + 33554432);
  u16*   a1r   = (u16*)(ws + 50331648);
  u16*   Ht    = (u16*)(ws + 67108864);
  u16*   Xwt   = (u16*)(ws + 83886080);
  float* cspa  = (float*)(ws + 84148224);
  float* diag1 = (float*)(ws + 84410368);
  float* ci1   = (float*)(ws + 84426752);
  float* w2v   = (float*)(ws + 84443136);
  float* diag2 = (float*)(ws + 84459520);
  float* dinv2 = (float*)(ws + 84475904);
  float* Zp    = (float*)(ws + 0);
  float* dp    = (float*)(ws + 16777216);
  float* cp    = (float*)(ws + 20971520);
  u16*   Yt    = (u16*)(ws + 25165824);
  float* Tp    = (float*)(ws + 50331648);

  conv_kernel<<<dim3(32, 32), 512, 0, stream>>>(A, w1, w2, w3, X, W, abf, bbt, a1t, a1r, Xwt);
  gemm_kernel<<<dim3(16, 16, 2), 256, 0, stream>>>(abf, bbt, Ht, cspa, diag1);
  zgemm_kernel<<<dim3(16, 16, 2), 256, 0, stream>>>(Ht, Xwt, Zp, cspa, diag1, ci1, w2v);
  dcol_kernel<<<dim3(256, 2), 256, 0, stream>>>(Ht, a1r, ci1, w2v, dp, cp);
  yfix_kernel<<<1024, 256, 0, stream>>>(Zp, ci1, diag1, Xwt, Yt, dp, cp, diag2, dinv2);
  tgemm_kernel<<<dim3(16, 16, 2), 256, 0, stream>>>(a1t, Yt, Tp);
  epilogue_kernel<<<1024, 256, 0, stream>>>(Tp, diag2, dinv2, Xwt, out);
}

// Round 8
// 224.300 us; speedup vs baseline: 1.3394x; 1.0960x over previous
//
#include <hip/hip_runtime.h>
#include <cstdint>
#include <cstddef>

typedef unsigned short u16;
typedef __attribute__((ext_vector_type(8))) short short8;
typedef __attribute__((ext_vector_type(4))) float v4f;

static constexpr size_t NN = (size_t)2048 * 2048;
#define N2 2048

typedef __attribute__((address_space(1))) const unsigned int guint;
typedef __attribute__((address_space(3))) unsigned int luint;

__device__ __forceinline__ float b2f_bits(uint32_t hi) { union { uint32_t u; float f; } v; v.u = hi; return v.f; }
__device__ __forceinline__ float b2f(u16 x) { return b2f_bits((uint32_t)x << 16); }
__device__ __forceinline__ u16 f2b(float f) {
  union { float f; uint32_t u; } v; v.f = f;
  uint32_t r = v.u + 0x7fffu + ((v.u >> 16) & 1u);
  return (u16)(r >> 16);
}
// HW packed f32->bf16 (RNE), 2 values/instr -- replaces ~6 integer ops.
__device__ __forceinline__ uint32_t cvt2(float lo, float hi) {
  uint32_t r;
  asm("v_cvt_pk_bf16_f32 %0, %1, %2" : "=v"(r) : "v"(lo), "v"(hi));
  return r;
}
__device__ __forceinline__ uint4 pack8(const float* f) {
  uint4 u;
  u.x = cvt2(f[0], f[1]);
  u.y = cvt2(f[2], f[3]);
  u.z = cvt2(f[4], f[5]);
  u.w = cvt2(f[6], f[7]);
  return u;
}
__device__ __forceinline__ void unp8(uint4 u, float* f) {
  f[0] = b2f_bits(u.x << 16); f[1] = b2f_bits(u.x & 0xffff0000u);
  f[2] = b2f_bits(u.y << 16); f[3] = b2f_bits(u.y & 0xffff0000u);
  f[4] = b2f_bits(u.z << 16); f[5] = b2f_bits(u.z & 0xffff0000u);
  f[6] = b2f_bits(u.w << 16); f[7] = b2f_bits(u.w & 0xffff0000u);
}
// wave-uniform value -> SGPR
__device__ __forceinline__ float sgprf(float x) {
  union { float f; int i; } v; v.f = x;
  v.i = __builtin_amdgcn_readfirstlane(v.i);
  return v.f;
}

// ---------------------------------------------------------------------------
// K0: one pass over fp32 A[5][N][N], 64x64 tiles, 512 threads. abf, a1r
// row-major; bbt, a1t transposed via XOR-swizzled two-phase LDS (16 KB).
// All bulk f32->bf16 via v_cvt_pk_bf16_f32. Blocks by<8 fold in Xw^T.
// ---------------------------------------------------------------------------
__global__ __launch_bounds__(512, 2) void conv_kernel(
    const float* __restrict__ A, const float* __restrict__ w1,
    const float* __restrict__ w2, const float* __restrict__ w3,
    const float* __restrict__ X, const float* __restrict__ W,
    u16* __restrict__ abf, u16* __restrict__ bbt, u16* __restrict__ a1t,
    u16* __restrict__ a1r, u16* __restrict__ Xwt)
{
  __shared__ u16 LT[2][64 * 64];   // [b_c, a1_c], transposed+swizzled
  const int t = threadIdx.x;
  const int i0 = blockIdx.y * 64, j0 = blockIdx.x * 64;
  const int m = t >> 3;            // tile row 0..63
  const int cg = t & 7;            // colgroup 0..7
  const int n0 = cg * 8;           // col base

  // softmax weights -> SGPRs
  float sc[3][2][5];
  {
    const float* wsrc[3] = { w1, w2, w3 };
    for (int q = 0; q < 3; ++q)
      for (int c = 0; c < 2; ++c) {
        float v[5], mx = -1e30f, sum = 0.f;
        #pragma unroll
        for (int e = 0; e < 5; ++e) { v[e] = wsrc[q][c * 5 + e]; mx = fmaxf(mx, v[e]); }
        #pragma unroll
        for (int e = 0; e < 5; ++e) { v[e] = expf(v[e] - mx); sum += v[e]; }
        #pragma unroll
        for (int e = 0; e < 5; ++e) sc[q][c][e] = sgprf(v[e] / sum);
      }
  }

  float av[2][8], bv[2][8], cv[2][8];
  #pragma unroll
  for (int c = 0; c < 2; ++c)
    #pragma unroll
    for (int u = 0; u < 8; ++u) { av[c][u] = 0.f; bv[c][u] = 0.f; cv[c][u] = 0.f; }

  #pragma unroll
  for (int e = 0; e < 5; ++e) {
    const float* base = A + (size_t)e * NN + (size_t)(i0 + m) * N2 + (j0 + n0);
    float4 x0 = ((const float4*)base)[0];
    float4 x1 = ((const float4*)base)[1];
    float f[8] = { x0.x, x0.y, x0.z, x0.w, x1.x, x1.y, x1.z, x1.w };
    #pragma unroll
    for (int c = 0; c < 2; ++c)
      #pragma unroll
      for (int u = 0; u < 8; ++u) {
        av[c][u] += sc[0][c][e] * f[u];
        bv[c][u] += sc[1][c][e] * f[u];
        cv[c][u] += sc[2][c][e] * f[u];
      }
  }

  // row-major outputs: 16B/lane, 8 lanes cover a 128B line
  #pragma unroll
  for (int c = 0; c < 2; ++c) {
    *(uint4*)(abf + (size_t)c * NN + (size_t)(i0 + m) * N2 + (j0 + n0)) = pack8(av[c]);
    *(uint4*)(a1r + (size_t)c * NN + (size_t)(i0 + m) * N2 + (j0 + n0)) = pack8(cv[c]);
  }
  // two-phase transposed stash (swizzled scalar stores, 2-way banks = free);
  // pairs converted via cvt_pk, halves split to rows u and u+1 (idx+64).
  const int swb = ((m >> 3) ^ cg) & 7;
  const int mlo = m & 7;
  const int on = t >> 3;          // output row (tile col n)
  const int mb = t & 7;           // m-block
  const int src = on * 64 + (((mb ^ (on >> 3)) & 7) * 8);
  #pragma unroll
  for (int c = 0; c < 2; ++c) {
    if (c == 1) __syncthreads();
    #pragma unroll
    for (int u = 0; u < 8; u += 2) {
      const int idx = (n0 + u) * 64 + swb * 8 + mlo;
      const uint32_t pb = cvt2(bv[c][u], bv[c][u + 1]);
      const uint32_t pc = cvt2(cv[c][u], cv[c][u + 1]);
      LT[0][idx]      = (u16)pb;
      LT[0][idx + 64] = (u16)(pb >> 16);
      LT[1][idx]      = (u16)pc;
      LT[1][idx + 64] = (u16)(pc >> 16);
    }
    __syncthreads();
    *(uint4*)(bbt + (size_t)c * NN + (size_t)(j0 + on) * N2 + (i0 + mb * 8)) =
        *(const uint4*)&LT[0][src];
    *(uint4*)(a1t + (size_t)c * NN + (size_t)(j0 + on) * N2 + (i0 + mb * 8)) =
        *(const uint4*)&LT[1][src];
  }
  // Folded Xw^T: 256 blocks x 8 rows = 2048 rows.
  if (blockIdx.y < 8) {
    const int n = (int)(blockIdx.y * 32 + blockIdx.x) * 8 + (t >> 6);
    const int k = t & 63;
    float acc = 0.f;
    for (int mm = 0; mm < 256; ++mm)
      acc += X[n * 256 + mm] * W[mm * 64 + k];
    Xwt[(size_t)k * N2 + n] = f2b(acc);
  }
}

// ---------------------------------------------------------------------------
// bf16 MFMA GEMM (glds staging, 128x128 tile, BK=64, 256 thr). C = A@B with
// A [M][K] bf16 row-major, Bt [N][K] bf16 K-contiguous. Emits column-sum
// partials csp[c][16][2048], diag[c][2048] (fp32), and Cout = bf16 C^T via
// two-half in-LDS transpose (cvt_pk packed stores).
// ---------------------------------------------------------------------------
__global__ __launch_bounds__(256, 3) void gemm_kernel(
    const u16* __restrict__ Ain, const u16* __restrict__ Btin,
    u16* __restrict__ Cout, float* __restrict__ csp, float* __restrict__ diag)
{
  const int c = blockIdx.z;
  const u16* Ac = Ain + (size_t)c * NN;
  const u16* Bc = Btin + (size_t)c * NN;
  const int m0 = blockIdx.y * 128, n0 = blockIdx.x * 128;
  const int t = threadIdx.x, w = t >> 6, lane = t & 63;
  const int quad = lane >> 4, r = lane & 15;
  __shared__ u16 SM[128 * 64 + 128 * 64];   // As | Bs (32 KB)
  u16* As = SM;
  u16* Bs = SM + 128 * 64;

  v4f zero4 = { 0.f, 0.f, 0.f, 0.f };
  v4f acc[2][8];
  #pragma unroll
  for (int i = 0; i < 2; ++i)
    #pragma unroll
    for (int j = 0; j < 8; ++j) acc[i][j] = zero4;

  const int srow = lane >> 3;            // row within an 8-row chunk
  const int sgran = (lane & 7) ^ srow;   // swizzled k-granule

  for (int kt = 0; kt < 2048; kt += 64) {
    __syncthreads();
    #pragma unroll
    for (int i = 0; i < 4; ++i) {
      const int chunk = i * 4 + w;
      const u16* ga = Ac + (size_t)(m0 + chunk * 8 + srow) * N2 + kt + sgran * 8;
      __builtin_amdgcn_global_load_lds((guint*)ga, (luint*)(As + chunk * 512), 16, 0, 0);
    }
    #pragma unroll
    for (int i = 0; i < 4; ++i) {
      const int chunk = i * 4 + w;
      const u16* gb = Bc + (size_t)(n0 + chunk * 8 + srow) * N2 + kt + sgran * 8;
      __builtin_amdgcn_global_load_lds((guint*)gb, (luint*)(Bs + chunk * 512), 16, 0, 0);
    }
    __syncthreads();
    #pragma unroll
    for (int ks = 0; ks < 2; ++ks) {
      const int sl = ((ks * 4 + quad) ^ (r & 7)) * 8;
      short8 af[2], bf[8];
      #pragma unroll
      for (int i = 0; i < 2; ++i)
        af[i] = *(const short8*)(As + (w * 32 + i * 16 + r) * 64 + sl);
      #pragma unroll
      for (int j = 0; j < 8; ++j)
        bf[j] = *(const short8*)(Bs + (j * 16 + r) * 64 + sl);
      #pragma unroll
      for (int i = 0; i < 2; ++i)
        #pragma unroll
        for (int j = 0; j < 8; ++j)
          acc[i][j] = __builtin_amdgcn_mfma_f32_16x16x32_bf16(af[i], bf[j], acc[i][j], 0, 0, 0);
    }
  }
  // C/D layout: col=lane&15, row=quad*4+reg (m89-verified). Diagonal fp32.
  if (blockIdx.x == blockIdx.y) {
    #pragma unroll
    for (int i = 0; i < 2; ++i) {
      const int rowg = m0 + w * 32 + i * 16 + quad * 4;
      #pragma unroll
      for (int j = 0; j < 8; ++j) {
        const int colg = n0 + j * 16 + r;
        #pragma unroll
        for (int g = 0; g < 4; ++g)
          if (rowg + g == colg) diag[c * N2 + colg] = acc[i][j][g];
      }
    }
  }
  // Column-sum partials over this block's 128 rows for its 128 cols.
  float s[8];
  #pragma unroll
  for (int j = 0; j < 8; ++j) {
    s[j] = 0.f;
    #pragma unroll
    for (int i = 0; i < 2; ++i)
      #pragma unroll
      for (int g = 0; g < 4; ++g) s[j] += acc[i][j][g];
    s[j] += __shfl_xor(s[j], 16);
    s[j] += __shfl_xor(s[j], 32);
  }
  __syncthreads();                 // MFMA-loop LDS reads done
  float* csl = (float*)SM;         // [4][128]
  if (quad == 0) {
    #pragma unroll
    for (int j = 0; j < 8; ++j) csl[w * 128 + j * 16 + r] = s[j];
  }
  __syncthreads();
  if (t < 128) {
    const float v = csl[t] + csl[128 + t] + csl[256 + t] + csl[384 + t];
    csp[((size_t)(c * 16) + blockIdx.y) * N2 + n0 + t] = v;
  }
  // Two-half transpose via LDS (row stride 136 u16 = 272 B, 8B-aligned
  // segment starts); packed cvt_pk 4B stores.
  {
    u16* tb = SM;                  // [64][136] u16 = 17.4 KB
    u16* Cc = Cout + (size_t)c * NN;
    #pragma unroll
    for (int h = 0; h < 2; ++h) {
      __syncthreads();
      #pragma unroll
      for (int i = 0; i < 2; ++i) {
        #pragma unroll
        for (int jl = 0; jl < 4; ++jl) {
          const int j = h * 4 + jl;
          uint32_t* dst = (uint32_t*)&tb[(jl * 16 + r) * 136 + (w * 32 + i * 16 + quad * 4)];
          dst[0] = cvt2(acc[i][j][0], acc[i][j][1]);
          dst[1] = cvt2(acc[i][j][2], acc[i][j][3]);
        }
      }
      __syncthreads();
      const int rown = t >> 2, seg = t & 3;
      const u16* ps = tb + rown * 136 + seg * 32;
      uint4* pd = (uint4*)(Cc + (size_t)(n0 + h * 64 + rown) * N2 + m0 + seg * 32);
      pd[0] = ((const uint4*)ps)[0];
      pd[1] = ((const uint4*)ps)[1];
      pd[2] = ((const uint4*)ps)[2];
      pd[3] = ((const uint4*)ps)[3];
    }
  }
}

// ---------------------------------------------------------------------------
// zgemm (+dcol fused, tail-free): per block (mt, split, c), K-split 16:
//   1) MFMA: Zp[split][c][k][i] partial over j in split's 128-range
//      (disjoint partial buffers -- no atomics, no waits).
//   2) recompute ci/wv slice for its 128 i-rows from csp/diag1 (L2-hot;
//      no cross-block hazard: inputs written by the previous kernel).
//      split==0 blocks also publish the ci slice for yfix (disjoint).
//   3) dcol elementwise over its 128x128 (i x j) region: Ht (L2-hot from
//      staging) + a1r (HBM) -> disjoint dp/cp slices [c][mt][split*128..].
// ---------------------------------------------------------------------------
__global__ __launch_bounds__(256, 2) void zgemm_kernel(
    const u16* __restrict__ Ht, const u16* __restrict__ Xwt,
    const u16* __restrict__ a1r, const float* __restrict__ csp,
    const float* __restrict__ diag1, float* __restrict__ Zp,
    float* __restrict__ ci, float* __restrict__ dp, float* __restrict__ cp)
{
  const int c = blockIdx.z, split = blockIdx.y, mt = blockIdx.x;
  const int m0 = mt * 128;
  const u16* Ac = Ht + (size_t)c * NN;
  const int t = threadIdx.x, w = t >> 6, lane = t & 63;
  const int quad = lane >> 4, r = lane & 15;
  __shared__ u16 SMZ[128 * 64 + 64 * 64];   // As | Bs (24 KB)
  u16* As = SMZ;
  u16* Bs = SMZ + 128 * 64;

  v4f zero4 = { 0.f, 0.f, 0.f, 0.f };
  v4f acc[2][4];
  #pragma unroll
  for (int i = 0; i < 2; ++i)
    #pragma unroll
    for (int j = 0; j < 4; ++j) acc[i][j] = zero4;

  const int srow = lane >> 3;
  const int sgran = (lane & 7) ^ srow;

  #pragma unroll
  for (int kk = 0; kk < 2; ++kk) {
    const int kt = split * 128 + kk * 64;
    __syncthreads();
    #pragma unroll
    for (int i = 0; i < 4; ++i) {
      const int chunk = i * 4 + w;
      const u16* ga = Ac + (size_t)(m0 + chunk * 8 + srow) * N2 + kt + sgran * 8;
      __builtin_amdgcn_global_load_lds((guint*)ga, (luint*)(As + chunk * 512), 16, 0, 0);
    }
    #pragma unroll
    for (int i = 0; i < 2; ++i) {
      const int chunk = i * 4 + w;
      const u16* gb = Xwt + (size_t)(chunk * 8 + srow) * N2 + kt + sgran * 8;
      __builtin_amdgcn_global_load_lds((guint*)gb, (luint*)(Bs + chunk * 512), 16, 0, 0);
    }
    __syncthreads();
    #pragma unroll
    for (int ks = 0; ks < 2; ++ks) {
      const int sl = ((ks * 4 + quad) ^ (r & 7)) * 8;
      short8 af[2], bf[4];
      #pragma unroll
      for (int i = 0; i < 2; ++i)
        af[i] = *(const short8*)(As + (w * 32 + i * 16 + r) * 64 + sl);
      #pragma unroll
      for (int j = 0; j < 4; ++j)
        bf[j] = *(const short8*)(Bs + (j * 16 + r) * 64 + sl);
      #pragma unroll
      for (int i = 0; i < 2; ++i)
        #pragma unroll
        for (int j = 0; j < 4; ++j)
          acc[i][j] = __builtin_amdgcn_mfma_f32_16x16x32_bf16(af[i], bf[j], acc[i][j], 0, 0, 0);
    }
  }
  const size_t pbase = (size_t)(split * 2 + c) * 64;
  #pragma unroll
  for (int i = 0; i < 2; ++i) {
    const int rowg = m0 + w * 32 + i * 16 + quad * 4;
    #pragma unroll
    for (int j = 0; j < 4; ++j) {
      const int colg = j * 16 + r;
      *(v4f*)(Zp + (pbase + colg) * (size_t)N2 + rowg) = acc[i][j];
    }
  }
  // --- ci/wv slice for this block's 128 rows (LDS floats [0..256)) ---
  __syncthreads();                       // MFMA LDS reads done; reuse SMZ
  float* ci_l = (float*)SMZ;             // [128]
  float* wv_l = ci_l + 128;              // [128]
  if (t < 128) {
    const int i = m0 + t;
    float cs = 0.f;
    #pragma unroll
    for (int s = 0; s < 16; ++s) cs += csp[((size_t)(c * 16) + s) * N2 + i];
    const float deg = cs - diag1[c * N2 + i];
    const float v = (deg == 0.f) ? 0.f : 1.f / (deg + 1e-8f);
    ci_l[t] = v;
    wv_l[t] = v * deg;
    if (split == 0) ci[c * N2 + i] = v;  // publish for yfix (disjoint slices)
  }
  __syncthreads();
  // --- dcol elementwise: thread = 4 cols (j4) x 8-row group (ig) per kk ---
  const int j4 = (t & 15) * 4, ig = t >> 4;
  float dacc[2][4], cacc[2][4];
  #pragma unroll
  for (int kk = 0; kk < 2; ++kk) {
    const int gj = split * 128 + kk * 64 + j4;
    #pragma unroll
    for (int u = 0; u < 4; ++u) { dacc[kk][u] = 0.f; cacc[kk][u] = 0.f; }
    for (int ii = 0; ii < 8; ++ii) {
      const int i = m0 + ig * 8 + ii;
      uint2 hu = *(const uint2*)(Ht  + (size_t)c * NN + (size_t)i * N2 + gj);
      uint2 au = *(const uint2*)(a1r + (size_t)c * NN + (size_t)i * N2 + gj);
      float h[4], a[4];
      h[0] = b2f_bits(hu.x << 16); h[1] = b2f_bits(hu.x & 0xffff0000u);
      h[2] = b2f_bits(hu.y << 16); h[3] = b2f_bits(hu.y & 0xffff0000u);
      a[0] = b2f_bits(au.x << 16); a[1] = b2f_bits(au.x & 0xffff0000u);
      a[2] = b2f_bits(au.y << 16); a[3] = b2f_bits(au.y & 0xffff0000u);
      const float cq = ci_l[ig * 8 + ii];
      const float wq = wv_l[ig * 8 + ii];
      #pragma unroll
      for (int u = 0; u < 4; ++u) {
        cacc[kk][u] += wq * a[u];
        const float tv = cq * h[u] * a[u];
        dacc[kk][u] += (i == gj + u) ? 0.f : tv;
      }
    }
  }
  // reduce over 16 ig-groups via LDS; dacc in cols [0,128), cacc in [128,256)
  float* red = ci_l + 256;               // [16][256] floats = 16 KB
  __syncthreads();
  #pragma unroll
  for (int kk = 0; kk < 2; ++kk)
    #pragma unroll
    for (int u = 0; u < 4; ++u) {
      red[ig * 256 + kk * 64 + j4 + u] = dacc[kk][u];
      red[ig * 256 + 128 + kk * 64 + j4 + u] = cacc[kk][u];
    }
  __syncthreads();
  {
    float v = 0.f;
    #pragma unroll
    for (int g = 0; g < 16; ++g) v += red[g * 256 + t];
    if (t < 128)
      dp[((size_t)(c * 16) + mt) * N2 + split * 128 + t] = v;
    else
      cp[((size_t)(c * 16) + mt) * N2 + split * 128 + (t - 128)] = v;
  }
}

// yfix: Y^T[c][k][i] = bf16( ci[i] * (Z[i][k] - diag1[i]*Xw[i][k]) ),
// Z reduced from 16 split partials. Blocks 0..15 additionally run fin
// (reduce dp/cp over 16 mt partials -> diag2/dinv2; inputs complete).
// ---------------------------------------------------------------------------
__global__ __launch_bounds__(256) void yfix_kernel(
    const float* __restrict__ Zp, const float* __restrict__ ci,
    const float* __restrict__ diag1, const u16* __restrict__ Xwt,
    u16* __restrict__ Yt, const float* __restrict__ dp,
    const float* __restrict__ cp, float* __restrict__ diag2,
    float* __restrict__ dinv2)
{
  const int idx = blockIdx.x * 256 + threadIdx.x;  // [0, 262144)
  const int i = idx & 2047, k = (idx >> 11) & 63, c = idx >> 17;
  float z = 0.f;
  #pragma unroll
  for (int s = 0; s < 16; ++s)
    z += Zp[(size_t)((s * 2 + c) * 64 + k) * N2 + i];
  const float xw = b2f(Xwt[(size_t)k * N2 + i]);
  const float y = ci[c * N2 + i] * (z - diag1[c * N2 + i] * xw);
  Yt[(size_t)c * 64 * N2 + (size_t)k * N2 + i] = f2b(y);
  // fused fin (16 of 1024 blocks)
  if (blockIdx.x < 16) {
    const int idx2 = blockIdx.x * 256 + threadIdx.x;  // [0, 4096)
    const int c2 = idx2 >> 11, i2 = idx2 & 2047;
    float ds = 0.f, cs = 0.f;
    #pragma unroll
    for (int b = 0; b < 16; ++b) {
      ds += dp[(size_t)(c2 * 16 + b) * N2 + i2];
      cs += cp[(size_t)(c2 * 16 + b) * N2 + i2];
    }
    const float deg = cs - ds + 1.0f;   // add=True: diag set to 1 -> +1
    diag2[idx2] = ds;
    dinv2[idx2] = (deg == 0.f) ? 0.f : 1.f / (deg + 1e-8f);
  }
}

// ---------------------------------------------------------------------------
// tgemm: Tp[split][c][i][k] partial of sum_j a1t[i][j]*Yt[c][k][j] over j in
// split's 128-range. K-split 16 -> 1024 blocks, 2+/CU.
// ---------------------------------------------------------------------------
__global__ __launch_bounds__(256, 2) void tgemm_kernel(
    const u16* __restrict__ a1t, const u16* __restrict__ Yt, float* __restrict__ Tp)
{
  const int c = blockIdx.z, split = blockIdx.y;
  const int m0 = blockIdx.x * 128;
  const u16* Ac = a1t + (size_t)c * NN;
  const u16* Bc = Yt + (size_t)c * (64 * (size_t)N2);
  const int t = threadIdx.x, w = t >> 6, lane = t & 63;
  const int quad = lane >> 4, r = lane & 15;
  __shared__ u16 As[128 * 64];
  __shared__ u16 Bs[64 * 64];

  v4f zero4 = { 0.f, 0.f, 0.f, 0.f };
  v4f acc[2][4];
  #pragma unroll
  for (int i = 0; i < 2; ++i)
    #pragma unroll
    for (int j = 0; j < 4; ++j) acc[i][j] = zero4;

  const int srow = lane >> 3;
  const int sgran = (lane & 7) ^ srow;

  #pragma unroll
  for (int kk = 0; kk < 2; ++kk) {
    const int kt = split * 128 + kk * 64;
    __syncthreads();
    #pragma unroll
    for (int i = 0; i < 4; ++i) {
      const int chunk = i * 4 + w;
      const u16* ga = Ac + (size_t)(m0 + chunk * 8 + srow) * N2 + kt + sgran * 8;
      __builtin_amdgcn_global_load_lds((guint*)ga, (luint*)(As + chunk * 512), 16, 0, 0);
    }
    #pragma unroll
    for (int i = 0; i < 2; ++i) {
      const int chunk = i * 4 + w;
      const u16* gb = Bc + (size_t)(chunk * 8 + srow) * N2 + kt + sgran * 8;
      __builtin_amdgcn_global_load_lds((guint*)gb, (luint*)(Bs + chunk * 512), 16, 0, 0);
    }
    __syncthreads();
    #pragma unroll
    for (int ks = 0; ks < 2; ++ks) {
      const int sl = ((ks * 4 + quad) ^ (r & 7)) * 8;
      short8 af[2], bf[4];
      #pragma unroll
      for (int i = 0; i < 2; ++i)
        af[i] = *(const short8*)(As + (w * 32 + i * 16 + r) * 64 + sl);
      #pragma unroll
      for (int j = 0; j < 4; ++j)
        bf[j] = *(const short8*)(Bs + (j * 16 + r) * 64 + sl);
      #pragma unroll
      for (int i = 0; i < 2; ++i)
        #pragma unroll
        for (int j = 0; j < 4; ++j)
          acc[i][j] = __builtin_amdgcn_mfma_f32_16x16x32_bf16(af[i], bf[j], acc[i][j], 0, 0, 0);
    }
  }
  const size_t pbase = (size_t)(split * 2 + c) * 2048;
  #pragma unroll
  for (int i = 0; i < 2; ++i) {
    const int rowg = m0 + w * 32 + i * 16 + quad * 4;
    #pragma unroll
    for (int j = 0; j < 4; ++j) {
      const int colg = j * 16 + r;
      #pragma unroll
      for (int g = 0; g < 4; ++g)
        Tp[(pbase + rowg + g) * 64 + colg] = acc[i][j][g];
    }
  }
}

// out[i][c*64+k] = relu( dinv2 * (T - diag2*xw + xw) ), fp32; T from 16 splits
__global__ void epilogue_kernel(const float* __restrict__ Tp, const float* __restrict__ diag2,
                                const float* __restrict__ dinv2, const u16* __restrict__ Xwt,
                                float* __restrict__ out)
{
  const int idx = blockIdx.x * 256 + threadIdx.x;
  const int k = idx & 63;
  const int c = (idx >> 6) & 1;
  const int i = idx >> 7;
  float T = 0.f;
  #pragma unroll
  for (int s = 0; s < 16; ++s)
    T += Tp[((size_t)(s * 2 + c) * 2048 + i) * 64 + k];
  const float hd = diag2[c * N2 + i];
  const float dv = dinv2[c * N2 + i];
  const float xw = b2f(Xwt[(size_t)k * N2 + i]);
  float v = dv * (T - hd * xw + xw);
  v = v > 0.f ? v : 0.f;
  out[(size_t)i * 128 + c * 64 + k] = v;
}

// ---------------------------------------------------------------------------
// Workspace layout (bytes), all reads preceded by writes, no cross-block sync:
//   abf   @ 0          (16.78 MB bf16)  -- dead after gemm1
//   bbt   @ 16777216   (16.78 MB bf16)  -- dead after gemm1
//   a1t   @ 33554432   (16.78 MB bf16)  -- dead after tgemm
//   a1r   @ 50331648   (16.78 MB bf16)  -- dead after zgemm
//   Ht    @ 67108864   (16.78 MB bf16)  -- dead after zgemm
//   Xwt   @ 83886080   (256 KB bf16 [64][2048])
//   cspa  @ 84148224   (256 KB fp32 [2][16][2048])
//   diag1 @ 84410368   (16 KB)
//   ci1   @ 84426752   (16 KB)
//   diag2 @ 84459520   (16 KB)
//   dinv2 @ 84475904   (16 KB)          -- end 84492288
//   Zp    @ 0          (16.78 MB fp32 [16][2][64][2048], over abf)
//   dp    @ 16777216   (256 KB fp32 [2][16][2048], over bbt)
//   cp    @ 17039360   (256 KB, over bbt)
//   Yt    @ 17301504   (512 KB bf16 [2][64][2048], over bbt)
//   Tp    @ 50331648   (16.78 MB fp32 [16][2][2048][64], over a1r)
// ---------------------------------------------------------------------------
extern "C" void kernel_launch(void* const* d_in, const int* in_sizes, int n_in,
                              void* d_out, int out_size, void* d_ws, size_t ws_size,
                              hipStream_t stream) {
  const float* A  = (const float*)d_in[0];
  const float* X  = (const float*)d_in[1];
  const float* w1 = (const float*)d_in[2];
  const float* w2 = (const float*)d_in[3];
  const float* w3 = (const float*)d_in[4];
  const float* W  = (const float*)d_in[5];
  float* out = (float*)d_out;
  char* ws = (char*)d_ws;

  u16*   abf   = (u16*)(ws + 0);
  u16*   bbt   = (u16*)(ws + 16777216);
  u16*   a1t   = (u16*)(ws + 33554432);
  u16*   a1r   = (u16*)(ws + 50331648);
  u16*   Ht    = (u16*)(ws + 67108864);
  u16*   Xwt   = (u16*)(ws + 83886080);
  float* cspa  = (float*)(ws + 84148224);
  float* diag1 = (float*)(ws + 84410368);
  float* ci1   = (float*)(ws + 84426752);
  float* diag2 = (float*)(ws + 84459520);
  float* dinv2 = (float*)(ws + 84475904);
  float* Zp    = (float*)(ws + 0);
  float* dp    = (float*)(ws + 16777216);
  float* cp    = (float*)(ws + 17039360);
  u16*   Yt    = (u16*)(ws + 17301504);
  float* Tp    = (float*)(ws + 50331648);

  conv_kernel<<<dim3(32, 32), 512, 0, stream>>>(A, w1, w2, w3, X, W, abf, bbt, a1t, a1r, Xwt);
  gemm_kernel<<<dim3(16, 16, 2), 256, 0, stream>>>(abf, bbt, Ht, cspa, diag1);
  zgemm_kernel<<<dim3(16, 16, 2), 256, 0, stream>>>(Ht, Xwt, a1r, cspa, diag1, Zp, ci1, dp, cp);
  yfix_kernel<<<1024, 256, 0, stream>>>(Zp, ci1, diag1, Xwt, Yt, dp, cp, diag2, dinv2);
  tgemm_kernel<<<dim3(16, 16, 2), 256, 0, stream>>>(a1t, Yt, Tp);
  epilogue_kernel<<<1024, 256, 0, stream>>>(Tp, diag2, dinv2, Xwt, out);
}